// Round 7
// baseline (360.947 us; speedup 1.0000x reference)
//
#include <hip/hip_runtime.h>
#include <stdint.h>

// Problem sizes (fixed by the reference)
#define BATCH 4096
#define EHC   1024                    // E = H = C
#define DCOMB 3072                    // D = E + H + C
#define NTOT  ((size_t)BATCH * EHC)   // 4M elements per [B, 1024] matrix
#define WGATE ((size_t)EHC * DCOMB)   // 1024*3072 per gate weight
#define WSML  ((size_t)EHC * EHC)     // 1024*1024 (Wh / Wc / Wp)

#define BK 64

typedef __bf16 bf16x8 __attribute__((ext_vector_type(8)));
typedef float  f32x4  __attribute__((ext_vector_type(4)));

__device__ inline unsigned short f2b(float f) {   // round-to-nearest-even bf16
    unsigned int x = __float_as_uint(f);
    unsigned int r = (x + 0x7fffu + ((x >> 16) & 1u)) >> 16;
    return (unsigned short)r;
}
__device__ inline float sigmoid_f(float x) { return 1.0f / (1.0f + __expf(-x)); }
__device__ inline float tanh_f(float x) {
    float xa = fminf(fmaxf(x, -15.0f), 15.0f);   // also kills NaN defensively
    float e = __expf(2.0f * xa);
    return (e - 1.0f) / (e + 1.0f);
}

__device__ inline void load16(const void* g, void* l) {
    __builtin_amdgcn_global_load_lds(
        (const __attribute__((address_space(1))) void*)g,
        (__attribute__((address_space(3))) void*)l, 16, 0, 0);
}

// Single fused fp32->bf16 conversion over the flat concatenation
//   [emb | hid | ctx | Wi | Wf | Wo | Wg | Wh | Wc | Wp]  ->  ws (contiguous).
__global__ __launch_bounds__(256)
void cvt_all(const float* __restrict__ s0, const float* __restrict__ s1,
             const float* __restrict__ s2, const float* __restrict__ s3,
             const float* __restrict__ s4, const float* __restrict__ s5,
             const float* __restrict__ s6, const float* __restrict__ s7,
             const float* __restrict__ s8, const float* __restrict__ s9,
             short* __restrict__ dst)
{
    const unsigned b = blockIdx.x;
    const float* src = s0; unsigned st = 0;
    if (b >= 2048)  { src = s1; st = 2048;  }
    if (b >= 4096)  { src = s2; st = 4096;  }
    if (b >= 6144)  { src = s3; st = 6144;  }
    if (b >= 7680)  { src = s4; st = 7680;  }
    if (b >= 9216)  { src = s5; st = 9216;  }
    if (b >= 10752) { src = s6; st = 10752; }
    if (b >= 12288) { src = s7; st = 12288; }
    if (b >= 12800) { src = s8; st = 12800; }
    if (b >= 13312) { src = s9; st = 13312; }
    size_t soff = ((size_t)(b - st) * 2048) + (size_t)threadIdx.x * 8;
    size_t doff = ((size_t)b * 2048) + (size_t)threadIdx.x * 8;
    float4 a = *(const float4*)(src + soff);
    float4 c = *(const float4*)(src + soff + 4);
    uint4 v;
    v.x = (unsigned)f2b(a.x) | ((unsigned)f2b(a.y) << 16);
    v.y = (unsigned)f2b(a.z) | ((unsigned)f2b(a.w) << 16);
    v.z = (unsigned)f2b(c.x) | ((unsigned)f2b(c.y) << 16);
    v.w = (unsigned)f2b(c.z) | ((unsigned)f2b(c.w) << 16);
    *(uint4*)(dst + doff) = v;
}

// ---------------------------------------------------------------------------
// Gates GEMM, R7: BMT=256 x BNT=64, 512 threads (8 waves), grid (16,16),
// mblk-chunk XCD swizzle.
//
// Why: R5/R6 decomposition showed (a) the whole-pipeline win needs ALL kernels
// row-chunk-aligned (gates on XCD r must WRITE rows [512r,512r+512) so MODE2/3
// on XCD r read them from local L2; worth ~40 us); (b) at BMT=128 that swizzle
// cost gates 27% because W logical traffic = (M/BMT) x 24MB = 768MB streamed
// from L3. BMT=256 halves W logical traffic to 384MB and the 2 resident
// A-panels (2 x 1.5MB) fit in the XCD's 4MB L2 -> gates can afford alignment.
//
// Swizzle: f' = (f&7)*32 + f>>3 (256 blocks, 256%8==0 bijection). XCD r gets
// mblk in {2r, 2r+1} = rows [512r, 512r+512)  — matches MODE2/3's chunking.
// Inner loop / K-order / fragment shapes identical to the proven kernel
// (MI=4, NI=2, NG=4, 2-barrier K-loop) -> bitwise-identical outputs.
// LDS: As 32KB + Bs 32KB = 64KB. acc = 128 AGPR. 1 block/CU, 8 waves.
// ---------------------------------------------------------------------------
__global__ __launch_bounds__(512, 2)
void gemm_gates(const short* __restrict__ A0, const short* __restrict__ A1,
                const short* __restrict__ A2, const short* __restrict__ W,
                const float* __restrict__ b0, const float* __restrict__ b1,
                const float* __restrict__ b2, const float* __restrict__ b3,
                const float* __restrict__ pcell,
                float* __restrict__ cell_o, float* __restrict__ hid_o,
                short* __restrict__ hid_b)
{
    int f = blockIdx.y * 16 + blockIdx.x;
    f = (f & 7) * 32 + (f >> 3);        // XCD r -> mblk {2r, 2r+1}
    const int nblk = f & 15;
    const int mblk = f >> 4;

    const int tid  = threadIdx.x;       // 0..511
    const int lane = tid & 63;
    const int wave = tid >> 6;          // 0..7
    const int wm   = wave >> 1;         // 0..3 : 64-row band
    const int wn   = wave & 1;          // 0..1 : 32-col band
    const int l15  = lane & 15;
    const int l4   = lane >> 4;

    __shared__ short As[256 * 64];      // 32 KB
    __shared__ short Bs[4 * 64 * 64];   // 32 KB

    // A staging: 2048 16B-chunks, 4 per thread. LDS chunk c holds global chunk
    // qg = (c&7)^(r&7) of row r (XOR swizzle, as in the proven kernel).
    int aoff[4];
#pragma unroll
    for (int j = 0; j < 4; j++) {
        int c  = j * 512 + tid;
        int r  = c >> 3;
        int qg = (c & 7) ^ (r & 7);
        aoff[j] = (mblk * 256 + r) * 1024 + qg * 8;
    }
    // W staging: per gate 512 chunks, exactly 1 per thread.
    int woff;
    {
        int r  = tid >> 3;              // 0..63
        int qg = (tid & 7) ^ (r & 7);
        woff = (nblk * 64 + r) * 3072 + qg * 8;
    }

    // LDS fragment-read offsets (elements). To read global chunk Q of row r,
    // read LDS chunk Q^(r&7)  (same involution as the write side).
    int a_ld[2][4], b_ld[2][2];
#pragma unroll
    for (int s = 0; s < 2; s++) {
        int qf = s * 4 + l4;
#pragma unroll
        for (int mi = 0; mi < 4; mi++) {
            int rowA = wm * 64 + mi * 16 + l15;
            a_ld[s][mi] = (rowA * 8 + (qf ^ (rowA & 7))) * 8;
        }
#pragma unroll
        for (int ni = 0; ni < 2; ni++) {
            int rowB = wn * 32 + ni * 16 + l15;
            b_ld[s][ni] = (rowB * 8 + (qf ^ (rowB & 7))) * 8;   // + g*4096
        }
    }

    f32x4 acc[4][4][2];
#pragma unroll
    for (int g = 0; g < 4; g++)
#pragma unroll
        for (int mi = 0; mi < 4; mi++)
#pragma unroll
            for (int ni = 0; ni < 2; ni++) acc[g][mi][ni] = (f32x4){0.f, 0.f, 0.f, 0.f};

    const int KT = DCOMB / BK;          // 48
    for (int kt = 0; kt < KT; ++kt) {
        const int k0   = kt * BK;
        const int seg  = k0 >> 10;
        const int acol = k0 & 1023;
        const short* Aseg = (seg == 0) ? A0 : (seg == 1) ? A1 : A2;

        __syncthreads();   // previous iteration's LDS reads done before overwrite
#pragma unroll
        for (int j = 0; j < 4; j++)
            load16(Aseg + aoff[j] + acol, &As[(j * 512 + tid) * 8]);
#pragma unroll
        for (int g = 0; g < 4; g++)
            load16(W + (size_t)g * WGATE + woff + k0, &Bs[(g * 512 + tid) * 8]);
        __syncthreads();   // compiler drains vmcnt before barrier -> LDS valid

#pragma unroll
        for (int s = 0; s < 2; s++) {
            bf16x8 af[4];
#pragma unroll
            for (int mi = 0; mi < 4; mi++) af[mi] = *(const bf16x8*)(As + a_ld[s][mi]);
#pragma unroll
            for (int g = 0; g < 4; g++) {
                bf16x8 bv[2];
#pragma unroll
                for (int ni = 0; ni < 2; ni++)
                    bv[ni] = *(const bf16x8*)(Bs + g * 4096 + b_ld[s][ni]);
#pragma unroll
                for (int mi = 0; mi < 4; mi++)
#pragma unroll
                    for (int ni = 0; ni < 2; ni++)
                        acc[g][mi][ni] = __builtin_amdgcn_mfma_f32_16x16x32_bf16(
                            af[mi], bv[ni], acc[g][mi][ni], 0, 0, 0);
            }
        }
    }

    // Epilogue: i,f,o,g -> cell/hidden. D layout: col=lane&15, row=4*(lane>>4)+reg.
#pragma unroll
    for (int ni = 0; ni < 2; ni++) {
        const int col = nblk * 64 + wn * 32 + ni * 16 + l15;
        const float bi_ = b0[col], bf_ = b1[col], bo_ = b2[col], bg_ = b3[col];
#pragma unroll
        for (int mi = 0; mi < 4; mi++) {
#pragma unroll
            for (int r = 0; r < 4; r++) {
                const size_t row = (size_t)(mblk * 256 + wm * 64 + mi * 16 + l4 * 4 + r);
                const size_t idx = row * 1024 + col;
                float ai  = fminf(fmaxf(acc[0][mi][ni][r] + bi_, -30.f), 30.f);
                float af_ = fminf(fmaxf(acc[1][mi][ni][r] + bf_, -30.f), 30.f);
                float ao  = fminf(fmaxf(acc[2][mi][ni][r] + bo_, -30.f), 30.f);
                float ag  = fminf(fmaxf(acc[3][mi][ni][r] + bg_, -30.f), 30.f);
                float ig = sigmoid_f(ai), fg = sigmoid_f(af_);
                float og = sigmoid_f(ao), gg = tanh_f(ag);
                float c = fg * pcell[idx] + ig * gg;
                float h = og * tanh_f(c);
                cell_o[idx] = c;
                hid_o[idx]  = h;
                hid_b[idx]  = (short)f2b(h);
            }
        }
    }
}

// Small follow-up GEMMs (R5-exact: BMT=128, mblk-chunked XCD swizzle).
// MODE 2 (resid): K=2048 segs {hidden,ctx} x {Wh,Wc}; +bh+bc+emb; bf16 out.
// MODE 3 (pred):  K=1024; +bp; f32 out.
template <int MODE>
__global__ __launch_bounds__(256, 2)
void gemm_fused(const short* __restrict__ A0, const short* __restrict__ A1,
                const short* __restrict__ A2,
                const short* __restrict__ W0, const short* __restrict__ W1,
                const short* __restrict__ W2, const short* __restrict__ W3,
                const float* __restrict__ b0, const float* __restrict__ b1,
                const float* __restrict__ b2, const float* __restrict__ b3,
                const float* __restrict__ extra,
                void* __restrict__ outv, float* __restrict__ out2,
                short* __restrict__ out3)
{
    constexpr int NG  = 1;
    constexpr int BMT = 128;
    constexpr int BNT = 64;
    constexpr int MI  = BMT / 32;
    constexpr int NI  = BNT / 32;
    constexpr int AI  = BMT / 32;
    constexpr int BI  = BNT / 32;
    constexpr int WMH = BMT / 2;
    constexpr int BSZ = BNT * BK;

    // mblk-chunked XCD bijection (512 wgs, 512 % 8 == 0): XCD r owns
    // mblk {4r..4r+3} = rows [512r, 512r+512) — aligned with the gates writer.
    int flat = blockIdx.y * 16 + blockIdx.x;
    flat = (flat & 7) * 64 + (flat >> 3);
    const int nblk = flat & 15;
    const int mblk = flat >> 4;

    const int tid  = threadIdx.x;
    const int lane = tid & 63;
    const int wave = tid >> 6;
    const int wm = wave >> 1;
    const int wn = wave & 1;
    const int l15 = lane & 15;
    const int l4  = lane >> 4;

    __shared__ short As[BMT * BK];
    __shared__ short Bs[NG * BSZ];

    const int K = (MODE == 2) ? 2048 : 1024;
    const int wstride = 1024;
    const int wrowbase = nblk * BNT;

    int aoff[AI], woff[BI];
#pragma unroll
    for (int j = 0; j < AI; j++) {
        int c  = j * 256 + tid;
        int r  = c >> 3;
        int qg = (c & 7) ^ (r & 7);
        aoff[j] = (mblk * BMT + r) * 1024 + qg * 8;
    }
#pragma unroll
    for (int j = 0; j < BI; j++) {
        int c  = j * 256 + tid;
        int r  = c >> 3;
        int qg = (c & 7) ^ (r & 7);
        woff[j] = (wrowbase + r) * wstride + qg * 8;
    }

    int a_ld[2][MI], b_ld[2][NI];
#pragma unroll
    for (int s = 0; s < 2; s++) {
        int q = s * 4 + l4;
#pragma unroll
        for (int i = 0; i < MI; i++) {
            int rowA = wm * WMH + i * 16 + l15;
            a_ld[s][i] = (rowA * 8 + (q ^ (rowA & 7))) * 8;
        }
#pragma unroll
        for (int i = 0; i < NI; i++) {
            int rowB = wn * 32 + i * 16 + l15;
            b_ld[s][i] = (rowB * 8 + (q ^ (rowB & 7))) * 8;
        }
    }

    f32x4 acc[NG][MI][NI];
#pragma unroll
    for (int g = 0; g < NG; g++)
#pragma unroll
        for (int i = 0; i < MI; i++)
#pragma unroll
            for (int j = 0; j < NI; j++) acc[g][i][j] = (f32x4){0.f, 0.f, 0.f, 0.f};

    const int KT = K / BK;
    for (int kt = 0; kt < KT; ++kt) {
        const int k0   = kt * BK;
        const int seg  = (MODE == 3) ? 0 : (k0 >> 10);
        const int acol = k0 & 1023;
        const short* Aseg = (seg == 0) ? A0 : A1;

        __syncthreads();
#pragma unroll
        for (int j = 0; j < AI; j++)
            load16(Aseg + aoff[j] + acol, &As[(j * 256 + tid) * 8]);
        {
            const short* Wt = (seg == 0) ? W0 : W1;
#pragma unroll
            for (int j = 0; j < BI; j++)
                load16(Wt + woff[j] + acol, &Bs[(j * 256 + tid) * 8]);
        }
        __syncthreads();

#pragma unroll
        for (int s = 0; s < 2; s++) {
            bf16x8 af[MI];
#pragma unroll
            for (int i = 0; i < MI; i++) af[i] = *(const bf16x8*)(As + a_ld[s][i]);
            bf16x8 bv[NI];
#pragma unroll
            for (int i = 0; i < NI; i++)
                bv[i] = *(const bf16x8*)(Bs + b_ld[s][i]);
#pragma unroll
            for (int mi = 0; mi < MI; mi++)
#pragma unroll
                for (int ni = 0; ni < NI; ni++)
                    acc[0][mi][ni] = __builtin_amdgcn_mfma_f32_16x16x32_bf16(
                        af[mi], bv[ni], acc[0][mi][ni], 0, 0, 0);
        }
    }

#pragma unroll
    for (int ni = 0; ni < NI; ni++) {
        const int col = nblk * BNT + wn * 32 + ni * 16 + l15;
        float bias_v = (MODE == 2) ? (b0[col] + b1[col]) : b0[col];
#pragma unroll
        for (int mi = 0; mi < MI; mi++) {
#pragma unroll
            for (int r = 0; r < 4; r++) {
                const size_t row = (size_t)(mblk * BMT + wm * WMH + mi * 16 + l4 * 4 + r);
                const size_t idx = row * 1024 + col;
                float v = acc[0][mi][ni][r] + bias_v;
                if (MODE == 2) {
                    v += extra[idx];                   // + emb (f32)
                    ((short*)outv)[idx] = (short)f2b(v);
                } else {
                    ((float*)outv)[idx] = v;
                }
            }
        }
    }
}

extern "C" void kernel_launch(void* const* d_in, const int* in_sizes, int n_in,
                              void* d_out, int out_size, void* d_ws, size_t ws_size,
                              hipStream_t stream)
{
    const float* emb  = (const float*)d_in[0];
    const float* hid  = (const float*)d_in[1];
    const float* pcel = (const float*)d_in[2];
    const float* ctx  = (const float*)d_in[3];
    const float* Wi = (const float*)d_in[4];   const float* bi = (const float*)d_in[5];
    const float* Wf = (const float*)d_in[6];   const float* bf_ = (const float*)d_in[7];
    const float* Wo = (const float*)d_in[8];   const float* bo = (const float*)d_in[9];
    const float* Wg = (const float*)d_in[10];  const float* bg = (const float*)d_in[11];
    const float* Wc = (const float*)d_in[12];  const float* bc = (const float*)d_in[13];
    const float* Wh = (const float*)d_in[14];  const float* bh = (const float*)d_in[15];
    const float* Wp = (const float*)d_in[16];  const float* bp = (const float*)d_in[17];

    float* out      = (float*)d_out;
    float* pred     = out;                       // [B,E] fp32
    float* hidden_o = out + NTOT;                // [B,H] fp32
    float* cell_o   = out + 2 * NTOT;            // [B,H] fp32

    // ws layout (bf16 shorts) — conversion order MUST stay contiguous for cvt_all:
    // [emb | hid | ctx | Wi | Wf | Wo | Wg | Wh | Wc | Wp] then scratch.
    short* ws = (short*)d_ws;
    short* w_emb  = ws;                          // 3 x NTOT activations
    short* w_hid  = ws + NTOT;
    short* w_ctx  = ws + 2 * NTOT;
    short* w_Wg4  = ws + 3 * NTOT;               // 4 x WGATE (Wi,Wf,Wo,Wg)
    short* w_Wh   = w_Wg4 + 4 * WGATE;
    short* w_Wc   = w_Wh + WSML;
    short* w_Wp   = w_Wc + WSML;
    short* w_hidb = w_Wp + WSML;                 // new hidden, bf16
    short* w_res  = w_hidb + NTOT;               // resid, bf16

    dim3 blk(256, 1, 1);
    const short* np16 = nullptr;
    const float* npf  = nullptr;

    // 0) one fused fp32->bf16 conversion pass (28.3M elems, 13824 blocks)
    hipLaunchKernelGGL(cvt_all, dim3(13824), blk, 0, stream,
                       emb, hid, ctx, Wi, Wf, Wo, Wg, Wh, Wc, Wp, ws);

    // 1) gates GEMM + cell/hidden epilogue (256x64 tiles, 512 thr, chain-aligned)
    hipLaunchKernelGGL(gemm_gates, dim3(16, 16), dim3(512, 1, 1), 0, stream,
                       w_emb, w_hid, w_ctx, w_Wg4,
                       bi, bf_, bo, bg, pcel,
                       cell_o, hidden_o, w_hidb);
    // 2) resid GEMM: K=2048 (hidden||ctx) x (Wh||Wc), + bh + bc + emb(fp32)
    hipLaunchKernelGGL((gemm_fused<2>), dim3(16, 32), blk, 0, stream,
                       w_hidb, w_ctx, np16, w_Wh, w_Wc, np16, np16,
                       bh, bc, npf, npf, emb, (void*)w_res, (float*)nullptr, (short*)nullptr);
    // 3) prediction GEMM: resid x Wp^T + bp -> fp32 out
    hipLaunchKernelGGL((gemm_fused<3>), dim3(16, 32), blk, 0, stream,
                       w_res, np16, np16, w_Wp, np16, np16, np16,
                       bp, npf, npf, npf, npf, (void*)pred, (float*)nullptr, (short*)nullptr);
}

// Round 8
// 335.637 us; speedup vs baseline: 1.0754x; 1.0754x over previous
//
#include <hip/hip_runtime.h>
#include <stdint.h>

// Problem sizes (fixed by the reference)
#define BATCH 4096
#define EHC   1024                    // E = H = C
#define DCOMB 3072                    // D = E + H + C
#define NTOT  ((size_t)BATCH * EHC)   // 4M elements per [B, 1024] matrix
#define WGATE ((size_t)EHC * DCOMB)   // 1024*3072 per gate weight
#define WSML  ((size_t)EHC * EHC)     // 1024*1024 (Wh / Wc / Wp)

#define BK 64

typedef __bf16 bf16x8 __attribute__((ext_vector_type(8)));
typedef float  f32x4  __attribute__((ext_vector_type(4)));

__device__ inline unsigned short f2b(float f) {   // round-to-nearest-even bf16
    unsigned int x = __float_as_uint(f);
    unsigned int r = (x + 0x7fffu + ((x >> 16) & 1u)) >> 16;
    return (unsigned short)r;
}
__device__ inline float sigmoid_f(float x) { return 1.0f / (1.0f + __expf(-x)); }
__device__ inline float tanh_f(float x) {
    float xa = fminf(fmaxf(x, -15.0f), 15.0f);   // also kills NaN defensively
    float e = __expf(2.0f * xa);
    return (e - 1.0f) / (e + 1.0f);
}

__device__ inline void load16(const void* g, void* l) {
    __builtin_amdgcn_global_load_lds(
        (const __attribute__((address_space(1))) void*)g,
        (__attribute__((address_space(3))) void*)l, 16, 0, 0);
}

// Single fused fp32->bf16 conversion over the flat concatenation
//   [emb | hid | ctx | Wi | Wf | Wo | Wg | Wh | Wc | Wp]  ->  ws (contiguous).
__global__ __launch_bounds__(256)
void cvt_all(const float* __restrict__ s0, const float* __restrict__ s1,
             const float* __restrict__ s2, const float* __restrict__ s3,
             const float* __restrict__ s4, const float* __restrict__ s5,
             const float* __restrict__ s6, const float* __restrict__ s7,
             const float* __restrict__ s8, const float* __restrict__ s9,
             short* __restrict__ dst)
{
    const unsigned b = blockIdx.x;
    const float* src = s0; unsigned st = 0;
    if (b >= 2048)  { src = s1; st = 2048;  }
    if (b >= 4096)  { src = s2; st = 4096;  }
    if (b >= 6144)  { src = s3; st = 6144;  }
    if (b >= 7680)  { src = s4; st = 7680;  }
    if (b >= 9216)  { src = s5; st = 9216;  }
    if (b >= 10752) { src = s6; st = 10752; }
    if (b >= 12288) { src = s7; st = 12288; }
    if (b >= 12800) { src = s8; st = 12800; }
    if (b >= 13312) { src = s9; st = 13312; }
    size_t soff = ((size_t)(b - st) * 2048) + (size_t)threadIdx.x * 8;
    size_t doff = ((size_t)b * 2048) + (size_t)threadIdx.x * 8;
    float4 a = *(const float4*)(src + soff);
    float4 c = *(const float4*)(src + soff + 4);
    uint4 v;
    v.x = (unsigned)f2b(a.x) | ((unsigned)f2b(a.y) << 16);
    v.y = (unsigned)f2b(a.z) | ((unsigned)f2b(a.w) << 16);
    v.z = (unsigned)f2b(c.x) | ((unsigned)f2b(c.y) << 16);
    v.w = (unsigned)f2b(c.z) | ((unsigned)f2b(c.w) << 16);
    *(uint4*)(dst + doff) = v;
}

// ---------------------------------------------------------------------------
// R8 gates: interleaved 8-phase (R2 geometry + fragment PREFETCH — the
// ds_read || MFMA || global_load interleave m196 proved is the lever).
//
// Block: 512 threads (8 waves: wm=wave>>1 row-band, wn=wave&1 col-band).
// Tile 256 x 64 x 4 gates, grid (16,16), no blockIdx swizzle (best measured).
// LDS 128 KiB double-buffered. K=3072 -> 48 tiles x 4 phases (1 gate each).
//
// Per phase G: [stage unit U_G(t+1)] [counted vmcnt] [s_barrier(mem)]
// [prefetch NEXT phase's 4 B-frag ds_read_b128] [MFMA x16 on frags read LAST
// phase] [G==3: prefetch af(t+1)+gate0(t+1) after MFMA] [s_barrier].
// So every MFMA cluster's LDS reads were issued a full phase earlier — the
// compiler's counted lgkmcnt is already satisfied (R2 serialized read->wait->
// MFMA every phase; that was the neutral-result defect).
//
// vmcnt ledger (units of 2 loads; verified by FIFO walk):
//   steady entering t.g0: outstanding = U3(t) [2]
//   g1: +U0,U1(t+1) -> 6; need U3(t) (gate2 prefetched at g1) -> vmcnt(4)
//   g3: +U2,U3(t+1) -> 8; need U0..U2(t+1) (af+gate0 prefetched at g3) -> vmcnt(2)
//   last tile: g1 vmcnt(0); no g3 prefetch.
// Barrier #1 is asm volatile + "memory" clobber so prefetch reads cannot hoist
// above it (Pn validity). Per-acc (t,s) MFMA order identical to the proven
// kernel -> bitwise-identical outputs.
// ---------------------------------------------------------------------------
template <int G>
__device__ __forceinline__ void gates_phase(
    bool pf, const short* __restrict__ An, const short* __restrict__ W,
    const int (&aoff)[2][2], const int (&adst)[2][2],
    const int (&boff)[2][2], const int (&bdst)[2][2],
    int k1, int ac1, short* lds, int P, int Pn,
    const int (&a_ld)[2][4], const int (&b_ld)[2][2],
    bf16x8 (&af)[2][4], bf16x8 (&cur)[2][2], bf16x8 (&nxt)[2][2],
    f32x4 (&accg)[4][2])
{
    // (1) stage one unit of tile t+1 into the dead parity buffer
    if (pf) {
        if (G < 2) {
#pragma unroll
            for (int j = 0; j < 2; j++)
                load16(An + aoff[G][j] + ac1, lds + Pn + adst[G][j]);
        } else {
#pragma unroll
            for (int j = 0; j < 2; j++)
                load16(W + boff[G - 2][j] + k1, lds + Pn + bdst[G - 2][j]);
        }
    }
    // (2) counted vmcnt per the ledger
    if (G == 1) {
        if (pf) asm volatile("s_waitcnt vmcnt(4)" ::: "memory");
        else    asm volatile("s_waitcnt vmcnt(0)" ::: "memory");
    }
    if (G == 3 && pf) asm volatile("s_waitcnt vmcnt(2)" ::: "memory");
    // (3) barrier #1 — memory clobber: prefetch reads below cannot hoist above
    asm volatile("s_barrier" ::: "memory");
    // (4) prefetch NEXT phase's B-fragments (gate G+1, same tile)
    if (G < 3) {
#pragma unroll
        for (int s = 0; s < 2; s++)
#pragma unroll
            for (int ni = 0; ni < 2; ni++)
                nxt[s][ni] = *(const bf16x8*)(lds + P + b_ld[s][ni] + (G + 1) * 4096);
    }
    // (5) MFMA cluster on fragments read a phase ago
    __builtin_amdgcn_s_setprio(1);
#pragma unroll
    for (int s = 0; s < 2; s++)
#pragma unroll
        for (int mi = 0; mi < 4; mi++)
#pragma unroll
            for (int ni = 0; ni < 2; ni++)
                accg[mi][ni] = __builtin_amdgcn_mfma_f32_16x16x32_bf16(
                    af[s][mi], cur[s][ni], accg[mi][ni], 0, 0, 0);
    __builtin_amdgcn_s_setprio(0);
    // (6) G==3: prefetch next TILE's A-frags + gate0 B-frags (after MFMA so
    //     tile t's af isn't clobbered; Pn validity from vmcnt(2)+barrier above)
    if (G == 3 && pf) {
#pragma unroll
        for (int s = 0; s < 2; s++)
#pragma unroll
            for (int mi = 0; mi < 4; mi++)
                af[s][mi] = *(const bf16x8*)(lds + Pn + a_ld[s][mi]);
#pragma unroll
        for (int s = 0; s < 2; s++)
#pragma unroll
            for (int ni = 0; ni < 2; ni++)
                nxt[s][ni] = *(const bf16x8*)(lds + Pn + b_ld[s][ni]);
    }
    // (7) barrier #2
    __builtin_amdgcn_s_barrier();
}

__global__ __launch_bounds__(512, 2)
void gemm_gates8(const short* __restrict__ A0, const short* __restrict__ A1,
                 const short* __restrict__ A2, const short* __restrict__ W,
                 const float* __restrict__ b0, const float* __restrict__ b1,
                 const float* __restrict__ b2, const float* __restrict__ b3,
                 const float* __restrict__ pcell,
                 float* __restrict__ cell_o, float* __restrict__ hid_o,
                 short* __restrict__ hid_b)
{
    const int nblk = blockIdx.x;   // N/64  = 16
    const int mblk = blockIdx.y;   // M/256 = 16
    const int tid  = threadIdx.x;  // 512
    const int lane = tid & 63;
    const int wave = tid >> 6;
    const int wm   = wave >> 1;    // 0..3  : 64-row band
    const int wn   = wave & 1;     // 0..1  : 32-col band
    const int l15  = lane & 15;
    const int l4   = lane >> 4;

    __shared__ short lds[65536];   // 128 KiB: [parity 32768][A 16384 | B 16384]

    // ---- staging offsets (global short-offsets sans k; LDS short dests) ----
    int aoff[2][2], adst[2][2];
#pragma unroll
    for (int u = 0; u < 2; u++)
#pragma unroll
        for (int j = 0; j < 2; j++) {
            int ca = u * 1024 + j * 512 + tid;      // A-tile chunk 0..2047
            int r  = ca >> 3, q = ca & 7;
            int qg = q ^ (r & 7);                   // XOR-swizzled global chunk
            aoff[u][j] = (mblk * 256 + r) * 1024 + qg * 8;
            adst[u][j] = ca * 8;                    // linear LDS
        }
    int boff[2][2], bdst[2][2];
#pragma unroll
    for (int u = 0; u < 2; u++)
#pragma unroll
        for (int j = 0; j < 2; j++) {
            int c2 = j * 512 + tid;                 // 0..1023 within gate-pair unit
            int g  = u * 2 + (c2 >> 9);             // U2={g0,g1}, U3={g2,g3}
            int rb = (c2 >> 3) & 63;
            int q  = c2 & 7;
            int qg = q ^ (rb & 7);
            boff[u][j] = g * (int)WGATE + (nblk * 64 + rb) * 3072 + qg * 8;
            bdst[u][j] = 16384 + (u * 1024 + c2) * 8;
        }

    // ---- fragment read offsets (shorts within one parity block) ----
    int a_ld[2][4], b_ld[2][2];
#pragma unroll
    for (int s = 0; s < 2; s++) {
        int qf = s * 4 + l4;
#pragma unroll
        for (int mi = 0; mi < 4; mi++) {
            int rowA = wm * 64 + mi * 16 + l15;
            a_ld[s][mi] = (rowA * 8 + (qf ^ (rowA & 7))) * 8;
        }
#pragma unroll
        for (int ni = 0; ni < 2; ni++) {
            int rowB = wn * 32 + ni * 16 + l15;
            b_ld[s][ni] = 16384 + (rowB * 8 + (qf ^ (rowB & 7))) * 8;  // + g*4096
        }
    }

    f32x4 acc[4][4][2];
#pragma unroll
    for (int g = 0; g < 4; g++)
#pragma unroll
        for (int mi = 0; mi < 4; mi++)
#pragma unroll
            for (int ni = 0; ni < 2; ni++) acc[g][mi][ni] = (f32x4){0.f, 0.f, 0.f, 0.f};

    // ---- prologue: stage tile 0 into parity 0; prefetch af + gate0 frags ----
#pragma unroll
    for (int u = 0; u < 2; u++)
#pragma unroll
        for (int j = 0; j < 2; j++)
            load16(A0 + aoff[u][j], lds + adst[u][j]);
#pragma unroll
    for (int u = 0; u < 2; u++)
#pragma unroll
        for (int j = 0; j < 2; j++)
            load16(W + boff[u][j], lds + bdst[u][j]);
    asm volatile("s_waitcnt vmcnt(2)" ::: "memory");   // U0,U1,U2(0) landed
    asm volatile("s_barrier" ::: "memory");

    bf16x8 af[2][4], bvA[2][2], bvB[2][2];
#pragma unroll
    for (int s = 0; s < 2; s++)
#pragma unroll
        for (int mi = 0; mi < 4; mi++)
            af[s][mi] = *(const bf16x8*)(lds + a_ld[s][mi]);
#pragma unroll
    for (int s = 0; s < 2; s++)
#pragma unroll
        for (int ni = 0; ni < 2; ni++)
            bvA[s][ni] = *(const bf16x8*)(lds + b_ld[s][ni]);   // gate 0

    const int KT = DCOMB / BK;                          // 48
#pragma unroll 1
    for (int t = 0; t < KT; ++t) {
        const int  P   = (t & 1) * 32768;
        const int  Pn  = P ^ 32768;
        const bool pf  = (t + 1 < KT);
        const int  k1  = (t + 1) * 64;
        const int  ac1 = k1 & 1023;
        const int  sn  = k1 >> 10;
        const short* An = (sn == 0) ? A0 : (sn == 1) ? A1 : A2;  // sn==3 unused

        gates_phase<0>(pf, An, W, aoff, adst, boff, bdst, k1, ac1, lds, P, Pn,
                       a_ld, b_ld, af, bvA, bvB, acc[0]);
        gates_phase<1>(pf, An, W, aoff, adst, boff, bdst, k1, ac1, lds, P, Pn,
                       a_ld, b_ld, af, bvB, bvA, acc[1]);
        gates_phase<2>(pf, An, W, aoff, adst, boff, bdst, k1, ac1, lds, P, Pn,
                       a_ld, b_ld, af, bvA, bvB, acc[2]);
        gates_phase<3>(pf, An, W, aoff, adst, boff, bdst, k1, ac1, lds, P, Pn,
                       a_ld, b_ld, af, bvB, bvA, acc[3]);
    }

    // ---- epilogue: i,f,o,g -> cell/hidden ----
#pragma unroll
    for (int ni = 0; ni < 2; ni++) {
        const int col = nblk * 64 + wn * 32 + ni * 16 + l15;
        const float bi_ = b0[col], bf_ = b1[col], bo_ = b2[col], bg_ = b3[col];
#pragma unroll
        for (int mi = 0; mi < 4; mi++) {
#pragma unroll
            for (int r = 0; r < 4; r++) {
                const size_t row = (size_t)(mblk * 256 + wm * 64 + mi * 16 + l4 * 4 + r);
                const size_t idx = row * 1024 + col;
                float ai  = fminf(fmaxf(acc[0][mi][ni][r] + bi_, -30.f), 30.f);
                float af_ = fminf(fmaxf(acc[1][mi][ni][r] + bf_, -30.f), 30.f);
                float ao  = fminf(fmaxf(acc[2][mi][ni][r] + bo_, -30.f), 30.f);
                float ag  = fminf(fmaxf(acc[3][mi][ni][r] + bg_, -30.f), 30.f);
                float ig = sigmoid_f(ai), fg = sigmoid_f(af_);
                float og = sigmoid_f(ao), gg = tanh_f(ag);
                float c = fg * pcell[idx] + ig * gg;
                float h = og * tanh_f(c);
                cell_o[idx] = c;
                hid_o[idx]  = h;
                hid_b[idx]  = (short)f2b(h);
            }
        }
    }
}

// Small follow-up GEMMs (BMT=128, mblk-chunked XCD swizzle).
// MODE 2 (resid): K=2048 segs {hidden,ctx} x {Wh,Wc}; +bh+bc+emb; bf16 out.
// MODE 3 (pred):  K=1024; +bp; f32 out.
template <int MODE>
__global__ __launch_bounds__(256, 2)
void gemm_fused(const short* __restrict__ A0, const short* __restrict__ A1,
                const short* __restrict__ A2,
                const short* __restrict__ W0, const short* __restrict__ W1,
                const short* __restrict__ W2, const short* __restrict__ W3,
                const float* __restrict__ b0, const float* __restrict__ b1,
                const float* __restrict__ b2, const float* __restrict__ b3,
                const float* __restrict__ extra,
                void* __restrict__ outv, float* __restrict__ out2,
                short* __restrict__ out3)
{
    constexpr int NG  = 1;
    constexpr int BMT = 128;
    constexpr int BNT = 64;
    constexpr int MI  = BMT / 32;
    constexpr int NI  = BNT / 32;
    constexpr int AI  = BMT / 32;
    constexpr int BI  = BNT / 32;
    constexpr int WMH = BMT / 2;
    constexpr int BSZ = BNT * BK;

    // mblk-chunked XCD bijection (512 wgs, 512 % 8 == 0).
    int flat = blockIdx.y * 16 + blockIdx.x;
    flat = (flat & 7) * 64 + (flat >> 3);
    const int nblk = flat & 15;
    const int mblk = flat >> 4;

    const int tid  = threadIdx.x;
    const int lane = tid & 63;
    const int wave = tid >> 6;
    const int wm = wave >> 1;
    const int wn = wave & 1;
    const int l15 = lane & 15;
    const int l4  = lane >> 4;

    __shared__ short As[BMT * BK];
    __shared__ short Bs[NG * BSZ];

    const int K = (MODE == 2) ? 2048 : 1024;
    const int wstride = 1024;
    const int wrowbase = nblk * BNT;

    int aoff[AI], woff[BI];
#pragma unroll
    for (int j = 0; j < AI; j++) {
        int c  = j * 256 + tid;
        int r  = c >> 3;
        int qg = (c & 7) ^ (r & 7);
        aoff[j] = (mblk * BMT + r) * 1024 + qg * 8;
    }
#pragma unroll
    for (int j = 0; j < BI; j++) {
        int c  = j * 256 + tid;
        int r  = c >> 3;
        int qg = (c & 7) ^ (r & 7);
        woff[j] = (wrowbase + r) * wstride + qg * 8;
    }

    int a_ld[2][MI], b_ld[2][NI];
#pragma unroll
    for (int s = 0; s < 2; s++) {
        int q = s * 4 + l4;
#pragma unroll
        for (int i = 0; i < MI; i++) {
            int rowA = wm * WMH + i * 16 + l15;
            a_ld[s][i] = (rowA * 8 + (q ^ (rowA & 7))) * 8;
        }
#pragma unroll
        for (int i = 0; i < NI; i++) {
            int rowB = wn * 32 + i * 16 + l15;
            b_ld[s][i] = (rowB * 8 + (q ^ (rowB & 7))) * 8;
        }
    }

    f32x4 acc[NG][MI][NI];
#pragma unroll
    for (int g = 0; g < NG; g++)
#pragma unroll
        for (int i = 0; i < MI; i++)
#pragma unroll
            for (int j = 0; j < NI; j++) acc[g][i][j] = (f32x4){0.f, 0.f, 0.f, 0.f};

    const int KT = K / BK;
    for (int kt = 0; kt < KT; ++kt) {
        const int k0   = kt * BK;
        const int seg  = (MODE == 3) ? 0 : (k0 >> 10);
        const int acol = k0 & 1023;
        const short* Aseg = (seg == 0) ? A0 : A1;

        __syncthreads();
#pragma unroll
        for (int j = 0; j < AI; j++)
            load16(Aseg + aoff[j] + acol, &As[(j * 256 + tid) * 8]);
        {
            const short* Wt = (seg == 0) ? W0 : W1;
#pragma unroll
            for (int j = 0; j < BI; j++)
                load16(Wt + woff[j] + acol, &Bs[(j * 256 + tid) * 8]);
        }
        __syncthreads();

#pragma unroll
        for (int s = 0; s < 2; s++) {
            bf16x8 af[MI];
#pragma unroll
            for (int i = 0; i < MI; i++) af[i] = *(const bf16x8*)(As + a_ld[s][i]);
            bf16x8 bv[NI];
#pragma unroll
            for (int i = 0; i < NI; i++)
                bv[i] = *(const bf16x8*)(Bs + b_ld[s][i]);
#pragma unroll
            for (int mi = 0; mi < MI; mi++)
#pragma unroll
                for (int ni = 0; ni < NI; ni++)
                    acc[0][mi][ni] = __builtin_amdgcn_mfma_f32_16x16x32_bf16(
                        af[mi], bv[ni], acc[0][mi][ni], 0, 0, 0);
        }
    }

#pragma unroll
    for (int ni = 0; ni < NI; ni++) {
        const int col = nblk * BNT + wn * 32 + ni * 16 + l15;
        float bias_v = (MODE == 2) ? (b0[col] + b1[col]) : b0[col];
#pragma unroll
        for (int mi = 0; mi < MI; mi++) {
#pragma unroll
            for (int r = 0; r < 4; r++) {
                const size_t row = (size_t)(mblk * BMT + wm * WMH + mi * 16 + l4 * 4 + r);
                const size_t idx = row * 1024 + col;
                float v = acc[0][mi][ni][r] + bias_v;
                if (MODE == 2) {
                    v += extra[idx];                   // + emb (f32)
                    ((short*)outv)[idx] = (short)f2b(v);
                } else {
                    ((float*)outv)[idx] = v;
                }
            }
        }
    }
}

extern "C" void kernel_launch(void* const* d_in, const int* in_sizes, int n_in,
                              void* d_out, int out_size, void* d_ws, size_t ws_size,
                              hipStream_t stream)
{
    const float* emb  = (const float*)d_in[0];
    const float* hid  = (const float*)d_in[1];
    const float* pcel = (const float*)d_in[2];
    const float* ctx  = (const float*)d_in[3];
    const float* Wi = (const float*)d_in[4];   const float* bi = (const float*)d_in[5];
    const float* Wf = (const float*)d_in[6];   const float* bf_ = (const float*)d_in[7];
    const float* Wo = (const float*)d_in[8];   const float* bo = (const float*)d_in[9];
    const float* Wg = (const float*)d_in[10];  const float* bg = (const float*)d_in[11];
    const float* Wc = (const float*)d_in[12];  const float* bc = (const float*)d_in[13];
    const float* Wh = (const float*)d_in[14];  const float* bh = (const float*)d_in[15];
    const float* Wp = (const float*)d_in[16];  const float* bp = (const float*)d_in[17];

    float* out      = (float*)d_out;
    float* pred     = out;                       // [B,E] fp32
    float* hidden_o = out + NTOT;                // [B,H] fp32
    float* cell_o   = out + 2 * NTOT;            // [B,H] fp32

    // ws layout (bf16 shorts) — conversion order MUST stay contiguous for cvt_all:
    // [emb | hid | ctx | Wi | Wf | Wo | Wg | Wh | Wc | Wp] then scratch.
    short* ws = (short*)d_ws;
    short* w_emb  = ws;                          // 3 x NTOT activations
    short* w_hid  = ws + NTOT;
    short* w_ctx  = ws + 2 * NTOT;
    short* w_Wg4  = ws + 3 * NTOT;               // 4 x WGATE (Wi,Wf,Wo,Wg)
    short* w_Wh   = w_Wg4 + 4 * WGATE;
    short* w_Wc   = w_Wh + WSML;
    short* w_Wp   = w_Wc + WSML;
    short* w_hidb = w_Wp + WSML;                 // new hidden, bf16
    short* w_res  = w_hidb + NTOT;               // resid, bf16

    dim3 blk(256, 1, 1);
    const short* np16 = nullptr;
    const float* npf  = nullptr;

    // 0) one fused fp32->bf16 conversion pass (28.3M elems, 13824 blocks)
    hipLaunchKernelGGL(cvt_all, dim3(13824), blk, 0, stream,
                       emb, hid, ctx, Wi, Wf, Wo, Wg, Wh, Wc, Wp, ws);

    // 1) interleaved 8-phase gates GEMM + cell/hidden epilogue (256x64x4, 512 thr)
    hipLaunchKernelGGL(gemm_gates8, dim3(16, 16), dim3(512, 1, 1), 0, stream,
                       w_emb, w_hid, w_ctx, w_Wg4,
                       bi, bf_, bo, bg, pcel,
                       cell_o, hidden_o, w_hidb);
    // 2) resid GEMM: K=2048 (hidden||ctx) x (Wh||Wc), + bh + bc + emb(fp32)
    hipLaunchKernelGGL((gemm_fused<2>), dim3(16, 32), blk, 0, stream,
                       w_hidb, w_ctx, np16, w_Wh, w_Wc, np16, np16,
                       bh, bc, npf, npf, emb, (void*)w_res, (float*)nullptr, (short*)nullptr);
    // 3) prediction GEMM: resid x Wp^T + bp -> fp32 out
    hipLaunchKernelGGL((gemm_fused<3>), dim3(16, 32), blk, 0, stream,
                       w_res, np16, np16, w_Wp, np16, np16, np16,
                       bp, npf, npf, npf, npf, (void*)pred, (float*)nullptr, (short*)nullptr);
}